// Round 21
// baseline (157.066 us; speedup 1.0000x reference)
//
#include <hip/hip_runtime.h>

typedef unsigned short ushort_t;
typedef __attribute__((ext_vector_type(8))) __bf16 bf16x8;
typedef __attribute__((ext_vector_type(4))) float f32x4;

#define EXP2F(x) __builtin_amdgcn_exp2f(x)
#define LOG2E 1.44269504088896340736f

// B=4, S=2048, E=1024, H=16, D=64, W=512. Inputs f32, OUTPUT f32.

__device__ __forceinline__ ushort_t f2bf(float f) {
  unsigned u = __float_as_uint(f);
  u += 0x7fffu + ((u >> 16) & 1u);   // RNE
  return (ushort_t)(u >> 16);
}

__device__ __forceinline__ f32x4 mfma16(bf16x8 a, bf16x8 b, f32x4 c) {
  return __builtin_amdgcn_mfma_f32_16x16x32_bf16(a, b, c, 0, 0, 0);
}

__device__ __forceinline__ void gload16(const ushort_t* g, ushort_t* l) {
  __builtin_amdgcn_global_load_lds((__attribute__((address_space(1))) void*)g,
                                   (__attribute__((address_space(3))) void*)l,
                                   16, 0, 0);
}

// one-shot f32->bf16 for two tensors (na, nb divisible by 1024).
__global__ __launch_bounds__(256) void cast_two(const float* __restrict__ a,
                                                ushort_t* __restrict__ oa, int na,
                                                const float* __restrict__ b,
                                                ushort_t* __restrict__ ob, int nb) {
  int i = (blockIdx.x * 256 + threadIdx.x) * 4;
  if (i < na) {
    float4 v = *(const float4*)(a + i);
    ushort4 o;
    o.x = f2bf(v.x); o.y = f2bf(v.y); o.z = f2bf(v.z); o.w = f2bf(v.w);
    *(ushort4*)(oa + i) = o;
  } else {
    int j = i - na;
    if (j < nb) {
      float4 v = *(const float4*)(b + j);
      ushort4 o;
      o.x = f2bf(v.x); o.y = f2bf(v.y); o.z = f2bf(v.z); o.w = f2bf(v.w);
      *(ushort4*)(ob + j) = o;
    }
  }
}

__global__ __launch_bounds__(256) void cast_f32_bf16(const float* __restrict__ in,
                                                     ushort_t* __restrict__ out, int n) {
  int i = (blockIdx.x * 256 + threadIdx.x) * 4;
  if (i < n) {
    float4 v = *(const float4*)(in + i);
    ushort4 o;
    o.x = f2bf(v.x); o.y = f2bf(v.y); o.z = f2bf(v.z); o.w = f2bf(v.w);
    *(ushort4*)(out + i) = o;
  }
}

// C[m][n] = sum_k A[m][k]*Bt[n][k]; A:[M,*] bf16 row-stride ldA, Bt:[N,K] bf16.
// 128x256 tile, BK=64, 8 waves (2Mx4N, 64x64 per wave), TRI-BUFFERED LDS
// (144KB) with counted-vmcnt pipeline (T3+T4): per K-tile two phases
// {ds_read || stage-issue(t+2); raw barrier; 16 MFMA; barrier} and ONE
// s_waitcnt vmcnt(6) per K-tile draining tile t+1's loads (issued 3 phases
// = ~700cyc earlier). Loads stay in flight across barriers (no __syncthreads
// vmcnt(0) drain). XOR-swizzle ((row&7) granule, both-sides). setprio.
// FUSE_V: blocks with col0>=2048 write V transposed+key-permuted into Vt.
template <bool C_F32, bool FUSE_V>
__global__ __launch_bounds__(512, 2) void gemm_bt(const ushort_t* __restrict__ A,
                                                  const ushort_t* __restrict__ Bt,
                                                  void* __restrict__ Cp,
                                                  ushort_t* __restrict__ Vt,
                                                  int N, int K, int ldA) {
  __shared__ ushort_t As[3][128 * 64];   // 3 x 16KB
  __shared__ ushort_t Bs[3][256 * 64];   // 3 x 32KB  -> 144KB total
  const int tid = threadIdx.x;           // 0..511
  const int wave = tid >> 6;
  const int lane = tid & 63;
  const int g = lane >> 4;
  const int q = lane & 15;
  const int qm = q & 7;
  const int wr = wave >> 2;              // 0..1 (M)
  const int wc = wave & 3;               // 0..3 (N)
  const int row0 = blockIdx.y * 128;
  const int col0 = blockIdx.x * 256;

  const f32x4 fzero = {0.f, 0.f, 0.f, 0.f};
  f32x4 acc[4][4];
#pragma unroll
  for (int i = 0; i < 4; ++i)
#pragma unroll
    for (int j = 0; j < 4; ++j) acc[i][j] = fzero;

  // staging: call u stages row u*64 + rs (rs = tid>>3, 0..63), source granule
  // (tid&7)^(rs&7); LDS dest linear u*4096 + tid*8 -> slot (row, tid&7).
  const int rs = tid >> 3;
  const int cs = (((tid & 7) ^ (rs & 7)) << 3);
  const ushort_t* ag = A + (size_t)(row0 + rs) * ldA + cs;
  const ushort_t* bg = Bt + (size_t)(col0 + rs) * K + cs;
  const int ld8 = tid * 8;

  // fragment-read granule: global (ks*4+g) ^ (row&7); row&7 == q&7.
  const int sw0 = ((g ^ qm) << 3);
  const int sw1 = (((4 + g) ^ qm) << 3);

#define STAGE6(bi, kt) {                                            \
    gload16(ag + (kt), &As[bi][ld8]);                               \
    gload16(ag + (size_t)64 * ldA + (kt), &As[bi][4096 + ld8]);     \
    gload16(bg + (kt), &Bs[bi][ld8]);                               \
    gload16(bg + (size_t)64 * K + (kt), &Bs[bi][4096 + ld8]);       \
    gload16(bg + (size_t)128 * K + (kt), &Bs[bi][8192 + ld8]);      \
    gload16(bg + (size_t)192 * K + (kt), &Bs[bi][12288 + ld8]);     \
  }

  const int nt = K >> 6;                 // 16 K-tiles
  STAGE6(0, 0)
  STAGE6(1, 64)
  asm volatile("s_waitcnt vmcnt(6)" ::: "memory");   // tile0 resident
  __builtin_amdgcn_s_barrier();

  for (int t = 0; t < nt; ++t) {
    const int kt = t << 6;
    const int cur = t % 3;
    const ushort_t* Ab = As[cur] + (wr * 64 + q) * 64;
    const ushort_t* Bb = Bs[cur] + (wc * 64 + q) * 64;

    // ---- phase ks=0: ds_read + stage-issue(t+2), barrier, MFMA, barrier
    {
      bf16x8 af[4], bfv[4];
#pragma unroll
      for (int mi = 0; mi < 4; ++mi)
        af[mi] = *(const bf16x8*)(Ab + mi * 1024 + sw0);
#pragma unroll
      for (int ni = 0; ni < 4; ++ni)
        bfv[ni] = *(const bf16x8*)(Bb + ni * 1024 + sw0);
      if (t + 2 < nt) { const int nb = (t + 2) % 3; STAGE6(nb, kt + 128) }
      __builtin_amdgcn_s_barrier();
      __builtin_amdgcn_s_setprio(1);
#pragma unroll
      for (int mi = 0; mi < 4; ++mi)
#pragma unroll
        for (int ni = 0; ni < 4; ++ni)
          acc[mi][ni] = mfma16(af[mi], bfv[ni], acc[mi][ni]);
      __builtin_amdgcn_s_setprio(0);
      __builtin_amdgcn_s_barrier();
    }

    // ---- phase ks=1: ds_read, counted vmcnt (drains tile t+1), barrier, MFMA
    {
      bf16x8 af[4], bfv[4];
#pragma unroll
      for (int mi = 0; mi < 4; ++mi)
        af[mi] = *(const bf16x8*)(Ab + mi * 1024 + sw1);
#pragma unroll
      for (int ni = 0; ni < 4; ++ni)
        bfv[ni] = *(const bf16x8*)(Bb + ni * 1024 + sw1);
      if (t + 2 < nt) asm volatile("s_waitcnt vmcnt(6)" ::: "memory");
      else            asm volatile("s_waitcnt vmcnt(0)" ::: "memory");
      __builtin_amdgcn_s_barrier();
      __builtin_amdgcn_s_setprio(1);
#pragma unroll
      for (int mi = 0; mi < 4; ++mi)
#pragma unroll
        for (int ni = 0; ni < 4; ++ni)
          acc[mi][ni] = mfma16(af[mi], bfv[ni], acc[mi][ni]);
      __builtin_amdgcn_s_setprio(0);
      __builtin_amdgcn_s_barrier();
    }
  }
#undef STAGE6

  if (FUSE_V && col0 >= 2048) {
    // V blocks: each (mi,ni) fragment -> one packed 8B store into Vt.
    // key k -> pos (k&~31) + 8g + 4*(mi&1) + r  ((rr>>4)&1 == mi&1 since
    // row0=128*by and wr*64 are even multiples of 16).
#pragma unroll
    for (int mi = 0; mi < 4; ++mi) {
      const int rr = row0 + wr * 64 + mi * 16 + 4 * g;   // r=0 row
      const int bb = rr >> 11;
      const int pbase = ((rr & 2047) & ~31) + 8 * g + 4 * (mi & 1);
#pragma unroll
      for (int ni = 0; ni < 4; ++ni) {
        const int cc = col0 + wc * 64 + ni * 16 + q - 2048;   // V-col index
        const int bh = bb * 16 + (cc >> 6);
        const int dd = cc & 63;
        ushort4 o;
        o.x = f2bf(acc[mi][ni][0]); o.y = f2bf(acc[mi][ni][1]);
        o.z = f2bf(acc[mi][ni][2]); o.w = f2bf(acc[mi][ni][3]);
        *(ushort4*)(Vt + (size_t)(bh * 64 + dd) * 2048 + pbase) = o;
      }
    }
  } else {
#pragma unroll
    for (int mi = 0; mi < 4; ++mi)
#pragma unroll
      for (int ni = 0; ni < 4; ++ni)
#pragma unroll
        for (int r = 0; r < 4; ++r) {
          size_t rr = (size_t)(row0 + wr * 64 + mi * 16 + 4 * g + r);
          size_t cc = (size_t)(col0 + wc * 64 + ni * 16 + q);
          if (C_F32) ((float*)Cp)[rr * N + cc] = acc[mi][ni][r];
          else ((ushort_t*)Cp)[rr * N + cc] = f2bf(acc[mi][ni][r]);
        }
  }
}

// Flash attention: block = 128 queries of one (b,h), 8 waves; K/V chunks
// (64 keys) LDS-double-buffered (global_load_lds, XOR-swizzled source).
// Swapped QK^T, zero-shuffle P (permuted Vt), defer-max, setprio,
// per-wave chunk skip + interior fast path.
// (512,4) = 2 blocks/CU: 4MB working set/XCD fits L2 ((512,8) thrashed).
__global__ __launch_bounds__(512, 4) void attn_kernel(const ushort_t* __restrict__ proj,
                                                      const ushort_t* __restrict__ Vt,
                                                      ushort_t* __restrict__ attn_out,
                                                      int ostride) {
  __shared__ ushort_t Ks[2][4096];
  __shared__ ushort_t Vs[2][4096];
  const int tid = threadIdx.x;
  const int wave = tid >> 6;
  const int lane = tid & 63;
  const int g = lane >> 4;
  const int q = lane & 15;
  const int bid = blockIdx.x;
  const int xcd = bid & 7;              // XCD-locality swizzle: 8 bh per XCD
  const int j = bid >> 3;               // 16 q-tiles per bh
  const int bh = xcd * 8 + (j >> 4);
  const int tile = j & 15;
  const int b = bh >> 4;
  const int h = bh & 15;
  const int q0b = tile * 128;           // block's 128 queries
  const int qw0 = q0b + wave * 16;      // this wave's 16 queries
  const int qglob = qw0 + q;

  const float slope2 = EXP2F(-(float)(h + 1) * 0.5f) * LOG2E;
  const float sc2 = 0.125f * LOG2E;

  const ushort_t* qptr = proj + (size_t)(b * 2048 + qglob) * 3072 + h * 64 + g * 8;
  const bf16x8 qa0 = *(const bf16x8*)(qptr);
  const bf16x8 qa1 = *(const bf16x8*)(qptr + 32);

  // staging: thread -> row tid>>3 (0..63), col-granule (tid&7)^(row&7)
  const int r0 = tid >> 3;
  const int c0s = (((tid & 7) ^ (r0 & 7)) << 3);
  const ushort_t* kgb = proj + (size_t)(b * 2048) * 3072 + 1024 + h * 64;
  const ushort_t* vgb = Vt + (size_t)(bh * 64) * 2048;

  // fragment-read swizzle: rows accessed are 16i+q -> row&7 == q&7
  const int qm = q & 7;
  const int sw0 = ((g ^ qm) << 3);
  const int sw1 = (((g + 4) ^ qm) << 3);

  const f32x4 fzero = {0.f, 0.f, 0.f, 0.f};
  f32x4 acc[4];
#pragma unroll
  for (int t2 = 0; t2 < 4; ++t2) acc[t2] = fzero;
  float m2 = -1e30f;
  float lsum = 0.f;
  const int relbase = qglob - 4 * g;

  int kc_lo = q0b - 512;
  if (kc_lo < 0) kc_lo = 0;             // q0b mult of 128 -> 64-aligned
  const int nch = ((q0b + 127 - kc_lo) >> 6) + 1;

#define STAGE(bi, kcv)                                                        \
  gload16(kgb + (size_t)((kcv) + r0) * 3072 + c0s, &Ks[bi][(size_t)tid * 8]); \
  gload16(vgb + (size_t)r0 * 2048 + (kcv) + c0s, &Vs[bi][(size_t)tid * 8]);

  STAGE(0, kc_lo)
  __syncthreads();

  for (int c = 0; c < nch; ++c) {
    const int kc = kc_lo + (c << 6);
    const ushort_t* Kb = Ks[c & 1];
    const ushort_t* Vb = Vs[c & 1];
    if (c + 1 < nch) { STAGE((c + 1) & 1, kc + 64) }

    // per-wave chunk relevance: any (query,key) pair with rel in [0,512)
    if (kc <= qw0 + 15 && kc >= qw0 - 574) {
      const int rbi = relbase - kc;
      float p[16];
      float mc = -1e30f;

      if (kc >= qw0 - 496 && kc <= qw0 - 63) {
        // interior: every rel valid -> mask-free scores
        const float bb = (float)rbi * slope2;
        __builtin_amdgcn_s_setprio(1);
#pragma unroll
        for (int i = 0; i < 4; ++i) {
          const int row = (i << 4) + q;
          bf16x8 ka = *(const bf16x8*)(Kb + row * 64 + sw0);
          bf16x8 kb = *(const bf16x8*)(Kb + row * 64 + sw1);
          f32x4 si = mfma16(kb, qa1, mfma16(ka, qa0, fzero));
#pragma unroll
          for (int r = 0; r < 4; ++r) {
            float sc = fmaf(si[r], sc2, bb) - (float)((i << 4) + r) * slope2;
            p[(i << 2) + r] = sc;
            mc = fmaxf(mc, sc);
          }
        }
        __builtin_amdgcn_s_setprio(0);
      } else {
        // edge: masked scores (sentinel -1e30 -> exp2 underflows to 0)
        __builtin_amdgcn_s_setprio(1);
#pragma unroll
        for (int i = 0; i < 4; ++i) {
          const int row = (i << 4) + q;
          bf16x8 ka = *(const bf16x8*)(Kb + row * 64 + sw0);
          bf16x8 kb = *(const bf16x8*)(Kb + row * 64 + sw1);
          f32x4 si = mfma16(kb, qa1, mfma16(ka, qa0, fzero));
#pragma unroll
          for (int r = 0; r < 4; ++r) {
            const int rel = rbi - ((i << 4) + r);
            float sc = ((unsigned)rel < 512u) ? fmaf(si[r], sc2, (float)rel * slope2)
                                              : -1e30f;
            p[(i << 2) + r] = sc;
            mc = fmaxf(mc, sc);
          }
        }
        __builtin_amdgcn_s_setprio(0);
      }

      if (__any(mc > m2 + 8.f)) {      // defer-max: rescale only on real bump
        float mg = fmaxf(mc, m2);
        mg = fmaxf(mg, __shfl_xor(mg, 16, 64));
        mg = fmaxf(mg, __shfl_xor(mg, 32, 64));
        const float factor = EXP2F(m2 - mg);
        lsum *= factor;
#pragma unroll
        for (int t2 = 0; t2 < 4; ++t2) acc[t2] *= factor;
        m2 = mg;
      }
#pragma unroll
      for (int i = 0; i < 16; ++i) p[i] = EXP2F(p[i] - m2);  // sentinel -> 0
      float ps0 = (p[0] + p[1]) + (p[2] + p[3]);
      float ps1 = (p[4] + p[5]) + (p[6] + p[7]);
      float ps2 = (p[8] + p[9]) + (p[10] + p[11]);
      float ps3 = (p[12] + p[13]) + (p[14] + p[15]);
      lsum += (ps0 + ps1) + (ps2 + ps3);

      bf16x8 pv0, pv1;                  // native casts -> v_cvt_pk_bf16_f32
#pragma unroll
      for (int r = 0; r < 4; ++r) {
        pv0[r] = (__bf16)p[r];       pv0[4 + r] = (__bf16)p[4 + r];
        pv1[r] = (__bf16)p[8 + r];   pv1[4 + r] = (__bf16)p[12 + r];
      }

      __builtin_amdgcn_s_setprio(1);
#pragma unroll
      for (int t2 = 0; t2 < 4; ++t2) {
        const int d = (t2 << 4) + q;
        bf16x8 vf0 = *(const bf16x8*)(Vb + d * 64 + sw0);
        bf16x8 vf1 = *(const bf16x8*)(Vb + d * 64 + sw1);
        acc[t2] = mfma16(vf0, pv0, acc[t2]);
        acc[t2] = mfma16(vf1, pv1, acc[t2]);
      }
      __builtin_amdgcn_s_setprio(0);
    }

    __syncthreads();                   // next buf ready; cur free to overwrite
  }
#undef STAGE

  lsum += __shfl_xor(lsum, 16, 64);
  lsum += __shfl_xor(lsum, 32, 64);
  const float inv = 1.f / lsum;

  ushort_t* ob = attn_out + (size_t)(b * 2048 + qglob) * ostride + h * 64;
#pragma unroll
  for (int t2 = 0; t2 < 4; ++t2)
#pragma unroll
    for (int r = 0; r < 4; ++r)
      ob[16 * t2 + 4 * g + r] = f2bf(acc[t2][r] * inv);
}

extern "C" void kernel_launch(void* const* d_in, const int* in_sizes, int n_in,
                              void* d_out, int out_size, void* d_ws, size_t ws_size,
                              hipStream_t stream) {
  const float* x = nullptr;      // 8388608
  const float* w_in = nullptr;   // 3145728
  const float* w_out = nullptr;  // 1048576
  for (int i = 0; i < n_in; ++i) {
    if (in_sizes[i] == 8388608) x = (const float*)d_in[i];
    else if (in_sizes[i] == 3145728) w_in = (const float*)d_in[i];
    else if (in_sizes[i] == 1048576) w_out = (const float*)d_in[i];
  }
  if (!(x && w_in && w_out)) { x = (const float*)d_in[0]; w_in = (const float*)d_in[1]; w_out = (const float*)d_in[2]; }

  char* ws = (char*)d_ws;
  // ws (64 MiB): proj bf16 [8192,3072] @0 (48Mi) — V cols written by attn only.
  //   xb bf16 @48Mi (16.8MB) — dead after gemm1 -> wob aliases it.
  // d_out scratch (32 MiB): wib bf16 @0 (6.3MB, dead after gemm1);
  //   Vt bf16 @8MiB (16.8MB, gemm1-written, attn-read, dead before gemm2).
  ushort_t* proj = (ushort_t*)(ws);
  ushort_t* xb   = (ushort_t*)(ws + (size_t)50331648);
  ushort_t* wob  = xb;
  ushort_t* wib  = (ushort_t*)d_out;
  ushort_t* Vt   = (ushort_t*)((char*)d_out + (size_t)8388608);

  cast_two<<<11264, 256, 0, stream>>>(x, xb, 8388608, w_in, wib, 3145728);
  gemm_bt<false, true><<<dim3(12, 64), 512, 0, stream>>>(xb, wib, proj, Vt, 3072, 1024, 1024);
  cast_f32_bf16<<<1024, 256, 0, stream>>>(w_out, wob, 1048576);   // xb dead now
  attn_kernel<<<1024, 512, 0, stream>>>(proj, Vt, proj + 2048, 3072);
  gemm_bt<true, false><<<dim3(4, 64), 512, 0, stream>>>(proj + 2048, wob, d_out, nullptr, 1024, 1024, 3072);
}

// Round 22
// 138.770 us; speedup vs baseline: 1.1318x; 1.1318x over previous
//
#include <hip/hip_runtime.h>

typedef unsigned short ushort_t;
typedef __attribute__((ext_vector_type(8))) __bf16 bf16x8;
typedef __attribute__((ext_vector_type(4))) float f32x4;

#define EXP2F(x) __builtin_amdgcn_exp2f(x)
#define LOG2E 1.44269504088896340736f

// B=4, S=2048, E=1024, H=16, D=64, W=512. Inputs f32, OUTPUT f32.

__device__ __forceinline__ ushort_t f2bf(float f) {
  unsigned u = __float_as_uint(f);
  u += 0x7fffu + ((u >> 16) & 1u);   // RNE
  return (ushort_t)(u >> 16);
}

__device__ __forceinline__ f32x4 mfma16(bf16x8 a, bf16x8 b, f32x4 c) {
  return __builtin_amdgcn_mfma_f32_16x16x32_bf16(a, b, c, 0, 0, 0);
}

__device__ __forceinline__ void gload16(const ushort_t* g, ushort_t* l) {
  __builtin_amdgcn_global_load_lds((__attribute__((address_space(1))) void*)g,
                                   (__attribute__((address_space(3))) void*)l,
                                   16, 0, 0);
}

// one-shot f32->bf16 for two tensors (na, nb divisible by 1024).
__global__ __launch_bounds__(256) void cast_two(const float* __restrict__ a,
                                                ushort_t* __restrict__ oa, int na,
                                                const float* __restrict__ b,
                                                ushort_t* __restrict__ ob, int nb) {
  int i = (blockIdx.x * 256 + threadIdx.x) * 4;
  if (i < na) {
    float4 v = *(const float4*)(a + i);
    ushort4 o;
    o.x = f2bf(v.x); o.y = f2bf(v.y); o.z = f2bf(v.z); o.w = f2bf(v.w);
    *(ushort4*)(oa + i) = o;
  } else {
    int j = i - na;
    if (j < nb) {
      float4 v = *(const float4*)(b + j);
      ushort4 o;
      o.x = f2bf(v.x); o.y = f2bf(v.y); o.z = f2bf(v.z); o.w = f2bf(v.w);
      *(ushort4*)(ob + j) = o;
    }
  }
}

// C[m][n] = sum_k A[m][k]*Bt[n][k]; A:[M,*] bf16 row-stride ldA, Bt:[N,K] bf16.
// 128x128 tile, BK=64, 4 waves, single-buffer 2-barrier: the measured local
// optimum (839 TF). Ledger: BK=64 dbuf (r13) 699TF/occupancy; BK=32 2-phase
// (r18/r19) 680-700TF even at 0 conflicts; tri-buffer counted-vmcnt 256-wide
// (r21) 640TF @1 block/CU. All restructures lose to implicit inter-block TLP.
// LDS XOR-swizzle ((row&7) 16B-granule, both-sides) + setprio.
// FUSE_V: blocks with col0>=2048 write the V-section transposed+key-permuted
// into Vt[bh*64+d][2048] (fragment's 4 reg values contiguous: key k ->
// pos (k&~31)+8g+4i+r) — replaces the transpose_v kernel.
template <bool C_F32, bool FUSE_V>
__global__ __launch_bounds__(256) void gemm_bt(const ushort_t* __restrict__ A,
                                               const ushort_t* __restrict__ Bt,
                                               void* __restrict__ Cp,
                                               ushort_t* __restrict__ Vt,
                                               int N, int K, int ldA) {
  __shared__ ushort_t As[128 * 64];
  __shared__ ushort_t Bs[128 * 64];
  const int tid = threadIdx.x;
  const int wave = tid >> 6;
  const int lane = tid & 63;
  const int g = lane >> 4;
  const int q = lane & 15;
  const int qm = q & 7;
  const int row0 = blockIdx.y * 128;
  const int col0 = blockIdx.x * 128;
  const int wm = (wave >> 1) * 64;
  const int wn = (wave & 1) * 64;

  const f32x4 fzero = {0.f, 0.f, 0.f, 0.f};
  f32x4 acc[4][4];
#pragma unroll
  for (int i = 0; i < 4; ++i)
#pragma unroll
    for (int j = 0; j < 4; ++j) acc[i][j] = fzero;

  const int rs = tid >> 3;             // ru = u*32 + rs; ru&7 == rs&7
  const int cs = (((tid & 7) ^ (rs & 7)) << 3);
  const ushort_t* ag = A + (size_t)(row0 + rs) * ldA + cs;
  const ushort_t* bg = Bt + (size_t)(col0 + rs) * K + cs;
  ushort_t* lA = As + (size_t)(wave * 64 + lane) * 8;   // wave-uniform + lane*16B
  ushort_t* lB = Bs + (size_t)(wave * 64 + lane) * 8;

  const int sw0 = ((g ^ qm) << 3);          // ks=0
  const int sw1 = (((4 + g) ^ qm) << 3);    // ks=1

  for (int kt = 0; kt < K; kt += 64) {
    __syncthreads();
#pragma unroll
    for (int u = 0; u < 4; ++u) {
      gload16(ag + (size_t)(u * 32) * ldA + kt, lA + u * 2048);
      gload16(bg + (size_t)(u * 32) * K + kt, lB + u * 2048);
    }
    __syncthreads();
#pragma unroll
    for (int ks = 0; ks < 2; ++ks) {
      const int sw = ks ? sw1 : sw0;
      bf16x8 af[4], bfv[4];
#pragma unroll
      for (int mi = 0; mi < 4; ++mi)
        af[mi] = *(const bf16x8*)(As + (wm + mi * 16 + q) * 64 + sw);
#pragma unroll
      for (int ni = 0; ni < 4; ++ni)
        bfv[ni] = *(const bf16x8*)(Bs + (wn + ni * 16 + q) * 64 + sw);
      __builtin_amdgcn_s_setprio(1);
#pragma unroll
      for (int mi = 0; mi < 4; ++mi)
#pragma unroll
        for (int ni = 0; ni < 4; ++ni)
          acc[mi][ni] = mfma16(af[mi], bfv[ni], acc[mi][ni]);
      __builtin_amdgcn_s_setprio(0);
    }
  }

  if (FUSE_V && col0 >= 2048) {
    // V blocks: each (mi,ni) fragment -> one packed 8B store into Vt.
#pragma unroll
    for (int mi = 0; mi < 4; ++mi) {
      const int rr = row0 + wm + mi * 16 + 4 * g;        // r=0 row
      const int bb = rr >> 11;
      const int pbase = ((rr & 2047) & ~31) + 8 * g + 4 * (mi & 1);
#pragma unroll
      for (int ni = 0; ni < 4; ++ni) {
        const int cc = col0 + wn + ni * 16 + q - 2048;   // V-col index
        const int bh = bb * 16 + (cc >> 6);
        const int dd = cc & 63;
        ushort4 o;
        o.x = f2bf(acc[mi][ni][0]); o.y = f2bf(acc[mi][ni][1]);
        o.z = f2bf(acc[mi][ni][2]); o.w = f2bf(acc[mi][ni][3]);
        *(ushort4*)(Vt + (size_t)(bh * 64 + dd) * 2048 + pbase) = o;
      }
    }
  } else {
#pragma unroll
    for (int mi = 0; mi < 4; ++mi)
#pragma unroll
      for (int ni = 0; ni < 4; ++ni)
#pragma unroll
        for (int r = 0; r < 4; ++r) {
          size_t rr = (size_t)(row0 + wm + mi * 16 + 4 * g + r);  // C/D row=4g+reg
          size_t cc = (size_t)(col0 + wn + ni * 16 + q);          // C/D col=lane&15
          if (C_F32) ((float*)Cp)[rr * N + cc] = acc[mi][ni][r];
          else ((ushort_t*)Cp)[rr * N + cc] = f2bf(acc[mi][ni][r]);
        }
  }
}

// Flash attention: block = 128 queries of one (b,h), 8 waves; K/V chunks
// (64 keys) LDS-double-buffered (global_load_lds, XOR-swizzled source).
// Swapped QK^T, zero-shuffle P (permuted Vt), defer-max, setprio,
// per-wave chunk skip + interior fast path.
// (512,4) = 2 blocks/CU: 4MB working set/XCD fits L2 ((512,8) thrashed).
// Blocks 0..15 instead cast w_out f32->bf16 into wob (folds away one launch;
// wob = dead xb region, untouched by attn, read by gemm2 after).
__global__ __launch_bounds__(512, 4) void attn_kernel(const ushort_t* __restrict__ proj,
                                                      const ushort_t* __restrict__ Vt,
                                                      ushort_t* __restrict__ attn_out,
                                                      const float* __restrict__ w_out,
                                                      ushort_t* __restrict__ wob,
                                                      int ostride) {
  const int bid = blockIdx.x;
  if (bid < 16) {                       // embedded w_out cast: 16 blocks,
    const int t = bid * 512 + threadIdx.x;             // coalesced float4
#pragma unroll 4
    for (int k = 0; k < 32; ++k) {
      int i = (k * 8192 + t) * 4;
      float4 v = *(const float4*)(w_out + i);
      ushort4 o;
      o.x = f2bf(v.x); o.y = f2bf(v.y); o.z = f2bf(v.z); o.w = f2bf(v.w);
      *(ushort4*)(wob + i) = o;
    }
    return;
  }
  const int bid2 = bid - 16;

  __shared__ ushort_t Ks[2][4096];
  __shared__ ushort_t Vs[2][4096];
  const int tid = threadIdx.x;
  const int wave = tid >> 6;
  const int lane = tid & 63;
  const int g = lane >> 4;
  const int q = lane & 15;
  const int xcd = bid2 & 7;             // XCD-locality swizzle: 8 bh per XCD
  const int j = bid2 >> 3;              // 16 q-tiles per bh
  const int bh = xcd * 8 + (j >> 4);
  const int tile = j & 15;
  const int b = bh >> 4;
  const int h = bh & 15;
  const int q0b = tile * 128;           // block's 128 queries
  const int qw0 = q0b + wave * 16;      // this wave's 16 queries
  const int qglob = qw0 + q;

  const float slope2 = EXP2F(-(float)(h + 1) * 0.5f) * LOG2E;
  const float sc2 = 0.125f * LOG2E;

  const ushort_t* qptr = proj + (size_t)(b * 2048 + qglob) * 3072 + h * 64 + g * 8;
  const bf16x8 qa0 = *(const bf16x8*)(qptr);
  const bf16x8 qa1 = *(const bf16x8*)(qptr + 32);

  // staging: thread -> row tid>>3 (0..63), col-granule (tid&7)^(row&7)
  const int r0 = tid >> 3;
  const int c0s = (((tid & 7) ^ (r0 & 7)) << 3);
  const ushort_t* kgb = proj + (size_t)(b * 2048) * 3072 + 1024 + h * 64;
  const ushort_t* vgb = Vt + (size_t)(bh * 64) * 2048;

  // fragment-read swizzle: rows accessed are 16i+q -> row&7 == q&7
  const int qm = q & 7;
  const int sw0 = ((g ^ qm) << 3);
  const int sw1 = (((g + 4) ^ qm) << 3);

  const f32x4 fzero = {0.f, 0.f, 0.f, 0.f};
  f32x4 acc[4];
#pragma unroll
  for (int t2 = 0; t2 < 4; ++t2) acc[t2] = fzero;
  float m2 = -1e30f;
  float lsum = 0.f;
  const int relbase = qglob - 4 * g;

  int kc_lo = q0b - 512;
  if (kc_lo < 0) kc_lo = 0;             // q0b mult of 128 -> 64-aligned
  const int nch = ((q0b + 127 - kc_lo) >> 6) + 1;

#define STAGE(bi, kcv)                                                        \
  gload16(kgb + (size_t)((kcv) + r0) * 3072 + c0s, &Ks[bi][(size_t)tid * 8]); \
  gload16(vgb + (size_t)r0 * 2048 + (kcv) + c0s, &Vs[bi][(size_t)tid * 8]);

  STAGE(0, kc_lo)
  __syncthreads();

  for (int c = 0; c < nch; ++c) {
    const int kc = kc_lo + (c << 6);
    const ushort_t* Kb = Ks[c & 1];
    const ushort_t* Vb = Vs[c & 1];
    if (c + 1 < nch) { STAGE((c + 1) & 1, kc + 64) }

    // per-wave chunk relevance: any (query,key) pair with rel in [0,512)
    if (kc <= qw0 + 15 && kc >= qw0 - 574) {
      const int rbi = relbase - kc;
      float p[16];
      float mc = -1e30f;

      if (kc >= qw0 - 496 && kc <= qw0 - 63) {
        // interior: every rel valid -> mask-free scores
        const float bb = (float)rbi * slope2;
        __builtin_amdgcn_s_setprio(1);
#pragma unroll
        for (int i = 0; i < 4; ++i) {
          const int row = (i << 4) + q;
          bf16x8 ka = *(const bf16x8*)(Kb + row * 64 + sw0);
          bf16x8 kb = *(const bf16x8*)(Kb + row * 64 + sw1);
          f32x4 si = mfma16(kb, qa1, mfma16(ka, qa0, fzero));
#pragma unroll
          for (int r = 0; r < 4; ++r) {
            float sc = fmaf(si[r], sc2, bb) - (float)((i << 4) + r) * slope2;
            p[(i << 2) + r] = sc;
            mc = fmaxf(mc, sc);
          }
        }
        __builtin_amdgcn_s_setprio(0);
      } else {
        // edge: masked scores (sentinel -1e30 -> exp2 underflows to 0)
        __builtin_amdgcn_s_setprio(1);
#pragma unroll
        for (int i = 0; i < 4; ++i) {
          const int row = (i << 4) + q;
          bf16x8 ka = *(const bf16x8*)(Kb + row * 64 + sw0);
          bf16x8 kb = *(const bf16x8*)(Kb + row * 64 + sw1);
          f32x4 si = mfma16(kb, qa1, mfma16(ka, qa0, fzero));
#pragma unroll
          for (int r = 0; r < 4; ++r) {
            const int rel = rbi - ((i << 4) + r);
            float sc = ((unsigned)rel < 512u) ? fmaf(si[r], sc2, (float)rel * slope2)
                                              : -1e30f;
            p[(i << 2) + r] = sc;
            mc = fmaxf(mc, sc);
          }
        }
        __builtin_amdgcn_s_setprio(0);
      }

      if (__any(mc > m2 + 8.f)) {      // defer-max: rescale only on real bump
        float mg = fmaxf(mc, m2);
        mg = fmaxf(mg, __shfl_xor(mg, 16, 64));
        mg = fmaxf(mg, __shfl_xor(mg, 32, 64));
        const float factor = EXP2F(m2 - mg);
        lsum *= factor;
#pragma unroll
        for (int t2 = 0; t2 < 4; ++t2) acc[t2] *= factor;
        m2 = mg;
      }
#pragma unroll
      for (int i = 0; i < 16; ++i) p[i] = EXP2F(p[i] - m2);  // sentinel -> 0
      float ps0 = (p[0] + p[1]) + (p[2] + p[3]);
      float ps1 = (p[4] + p[5]) + (p[6] + p[7]);
      float ps2 = (p[8] + p[9]) + (p[10] + p[11]);
      float ps3 = (p[12] + p[13]) + (p[14] + p[15]);
      lsum += (ps0 + ps1) + (ps2 + ps3);

      bf16x8 pv0, pv1;                  // native casts -> v_cvt_pk_bf16_f32
#pragma unroll
      for (int r = 0; r < 4; ++r) {
        pv0[r] = (__bf16)p[r];       pv0[4 + r] = (__bf16)p[4 + r];
        pv1[r] = (__bf16)p[8 + r];   pv1[4 + r] = (__bf16)p[12 + r];
      }

      __builtin_amdgcn_s_setprio(1);
#pragma unroll
      for (int t2 = 0; t2 < 4; ++t2) {
        const int d = (t2 << 4) + q;
        bf16x8 vf0 = *(const bf16x8*)(Vb + d * 64 + sw0);
        bf16x8 vf1 = *(const bf16x8*)(Vb + d * 64 + sw1);
        acc[t2] = mfma16(vf0, pv0, acc[t2]);
        acc[t2] = mfma16(vf1, pv1, acc[t2]);
      }
      __builtin_amdgcn_s_setprio(0);
    }

    __syncthreads();                   // next buf ready; cur free to overwrite
  }
#undef STAGE

  lsum += __shfl_xor(lsum, 16, 64);
  lsum += __shfl_xor(lsum, 32, 64);
  const float inv = 1.f / lsum;

  ushort_t* ob = attn_out + (size_t)(b * 2048 + qglob) * ostride + h * 64;
#pragma unroll
  for (int t2 = 0; t2 < 4; ++t2)
#pragma unroll
    for (int r = 0; r < 4; ++r)
      ob[16 * t2 + 4 * g + r] = f2bf(acc[t2][r] * inv);
}

extern "C" void kernel_launch(void* const* d_in, const int* in_sizes, int n_in,
                              void* d_out, int out_size, void* d_ws, size_t ws_size,
                              hipStream_t stream) {
  const float* x = nullptr;      // 8388608
  const float* w_in = nullptr;   // 3145728
  const float* w_out = nullptr;  // 1048576
  for (int i = 0; i < n_in; ++i) {
    if (in_sizes[i] == 8388608) x = (const float*)d_in[i];
    else if (in_sizes[i] == 3145728) w_in = (const float*)d_in[i];
    else if (in_sizes[i] == 1048576) w_out = (const float*)d_in[i];
  }
  if (!(x && w_in && w_out)) { x = (const float*)d_in[0]; w_in = (const float*)d_in[1]; w_out = (const float*)d_in[2]; }

  char* ws = (char*)d_ws;
  // ws (64 MiB): proj bf16 [8192,3072] @0 (48Mi) — V cols written by attn only.
  //   xb bf16 @48Mi (16.8MB) — dead after gemm1 -> wob aliases it (cast
  //   embedded in the attn launch).
  // d_out scratch (32 MiB): wib bf16 @0 (6.3MB, dead after gemm1);
  //   Vt bf16 @8MiB (16.8MB, gemm1-written, attn-read, dead before gemm2).
  ushort_t* proj = (ushort_t*)(ws);
  ushort_t* xb   = (ushort_t*)(ws + (size_t)50331648);
  ushort_t* wob  = xb;
  ushort_t* wib  = (ushort_t*)d_out;
  ushort_t* Vt   = (ushort_t*)((char*)d_out + (size_t)8388608);

  cast_two<<<11264, 256, 0, stream>>>(x, xb, 8388608, w_in, wib, 3145728);
  gemm_bt<false, true><<<dim3(24, 64), 256, 0, stream>>>(xb, wib, proj, Vt, 3072, 1024, 1024);
  attn_kernel<<<1040, 512, 0, stream>>>(proj, Vt, proj + 2048, w_out, wob, 3072);
  gemm_bt<true, false><<<dim3(8, 64), 256, 0, stream>>>(proj + 2048, wob, d_out, nullptr, 1024, 1024, 3072);
}

// Round 23
// 137.616 us; speedup vs baseline: 1.1413x; 1.0084x over previous
//
#include <hip/hip_runtime.h>

typedef unsigned short ushort_t;
typedef __attribute__((ext_vector_type(8))) __bf16 bf16x8;
typedef __attribute__((ext_vector_type(4))) float f32x4;

#define EXP2F(x) __builtin_amdgcn_exp2f(x)
#define LOG2E 1.44269504088896340736f

// B=4, S=2048, E=1024, H=16, D=64, W=512. Inputs f32, OUTPUT f32.

__device__ __forceinline__ ushort_t f2bf(float f) {
  unsigned u = __float_as_uint(f);
  u += 0x7fffu + ((u >> 16) & 1u);   // RNE
  return (ushort_t)(u >> 16);
}

__device__ __forceinline__ f32x4 mfma16(bf16x8 a, bf16x8 b, f32x4 c) {
  return __builtin_amdgcn_mfma_f32_16x16x32_bf16(a, b, c, 0, 0, 0);
}

__device__ __forceinline__ void gload16(const ushort_t* g, ushort_t* l) {
  __builtin_amdgcn_global_load_lds((__attribute__((address_space(1))) void*)g,
                                   (__attribute__((address_space(3))) void*)l,
                                   16, 0, 0);
}

// one-shot f32->bf16 for two tensors (na, nb divisible by 1024).
__global__ __launch_bounds__(256) void cast_two(const float* __restrict__ a,
                                                ushort_t* __restrict__ oa, int na,
                                                const float* __restrict__ b,
                                                ushort_t* __restrict__ ob, int nb) {
  int i = (blockIdx.x * 256 + threadIdx.x) * 4;
  if (i < na) {
    float4 v = *(const float4*)(a + i);
    ushort4 o;
    o.x = f2bf(v.x); o.y = f2bf(v.y); o.z = f2bf(v.z); o.w = f2bf(v.w);
    *(ushort4*)(oa + i) = o;
  } else {
    int j = i - na;
    if (j < nb) {
      float4 v = *(const float4*)(b + j);
      ushort4 o;
      o.x = f2bf(v.x); o.y = f2bf(v.y); o.z = f2bf(v.z); o.w = f2bf(v.w);
      *(ushort4*)(ob + j) = o;
    }
  }
}

// C[m][n] = sum_k A[m][k]*Bt[n][k]; A:[M,*] bf16 row-stride ldA, Bt:[N,K] bf16.
// 128x128 tile, BK=64, 4 waves, single-buffer 2-barrier: the measured local
// optimum (839 TF). Ledger: BK=64 dbuf (r13) 699TF/occupancy; BK=32 2-phase
// (r18/r19) 680-700TF even at 0 conflicts; tri-buffer counted-vmcnt 256-wide
// (r21) 640TF @1 block/CU. All restructures lose to implicit inter-block TLP.
// LDS XOR-swizzle ((row&7) 16B-granule, both-sides) + setprio.
// FUSE_V: blocks with col0>=2048 write the V-section transposed+key-permuted
// into Vt[bh*64+d][2048] (fragment's 4 reg values contiguous: key k ->
// pos (k&~31)+8g+4i+r) — replaces the transpose_v kernel.
template <bool C_F32, bool FUSE_V>
__global__ __launch_bounds__(256) void gemm_bt(const ushort_t* __restrict__ A,
                                               const ushort_t* __restrict__ Bt,
                                               void* __restrict__ Cp,
                                               ushort_t* __restrict__ Vt,
                                               int N, int K, int ldA) {
  __shared__ ushort_t As[128 * 64];
  __shared__ ushort_t Bs[128 * 64];
  const int tid = threadIdx.x;
  const int wave = tid >> 6;
  const int lane = tid & 63;
  const int g = lane >> 4;
  const int q = lane & 15;
  const int qm = q & 7;
  const int row0 = blockIdx.y * 128;
  const int col0 = blockIdx.x * 128;
  const int wm = (wave >> 1) * 64;
  const int wn = (wave & 1) * 64;

  const f32x4 fzero = {0.f, 0.f, 0.f, 0.f};
  f32x4 acc[4][4];
#pragma unroll
  for (int i = 0; i < 4; ++i)
#pragma unroll
    for (int j = 0; j < 4; ++j) acc[i][j] = fzero;

  const int rs = tid >> 3;             // ru = u*32 + rs; ru&7 == rs&7
  const int cs = (((tid & 7) ^ (rs & 7)) << 3);
  const ushort_t* ag = A + (size_t)(row0 + rs) * ldA + cs;
  const ushort_t* bg = Bt + (size_t)(col0 + rs) * K + cs;
  ushort_t* lA = As + (size_t)(wave * 64 + lane) * 8;   // wave-uniform + lane*16B
  ushort_t* lB = Bs + (size_t)(wave * 64 + lane) * 8;

  const int sw0 = ((g ^ qm) << 3);          // ks=0
  const int sw1 = (((4 + g) ^ qm) << 3);    // ks=1

  for (int kt = 0; kt < K; kt += 64) {
    __syncthreads();
#pragma unroll
    for (int u = 0; u < 4; ++u) {
      gload16(ag + (size_t)(u * 32) * ldA + kt, lA + u * 2048);
      gload16(bg + (size_t)(u * 32) * K + kt, lB + u * 2048);
    }
    __syncthreads();
#pragma unroll
    for (int ks = 0; ks < 2; ++ks) {
      const int sw = ks ? sw1 : sw0;
      bf16x8 af[4], bfv[4];
#pragma unroll
      for (int mi = 0; mi < 4; ++mi)
        af[mi] = *(const bf16x8*)(As + (wm + mi * 16 + q) * 64 + sw);
#pragma unroll
      for (int ni = 0; ni < 4; ++ni)
        bfv[ni] = *(const bf16x8*)(Bs + (wn + ni * 16 + q) * 64 + sw);
      __builtin_amdgcn_s_setprio(1);
#pragma unroll
      for (int mi = 0; mi < 4; ++mi)
#pragma unroll
        for (int ni = 0; ni < 4; ++ni)
          acc[mi][ni] = mfma16(af[mi], bfv[ni], acc[mi][ni]);
      __builtin_amdgcn_s_setprio(0);
    }
  }

  if (FUSE_V && col0 >= 2048) {
    // V blocks: each (mi,ni) fragment -> one packed 8B store into Vt.
#pragma unroll
    for (int mi = 0; mi < 4; ++mi) {
      const int rr = row0 + wm + mi * 16 + 4 * g;        // r=0 row
      const int bb = rr >> 11;
      const int pbase = ((rr & 2047) & ~31) + 8 * g + 4 * (mi & 1);
#pragma unroll
      for (int ni = 0; ni < 4; ++ni) {
        const int cc = col0 + wn + ni * 16 + q - 2048;   // V-col index
        const int bh = bb * 16 + (cc >> 6);
        const int dd = cc & 63;
        ushort4 o;
        o.x = f2bf(acc[mi][ni][0]); o.y = f2bf(acc[mi][ni][1]);
        o.z = f2bf(acc[mi][ni][2]); o.w = f2bf(acc[mi][ni][3]);
        *(ushort4*)(Vt + (size_t)(bh * 64 + dd) * 2048 + pbase) = o;
      }
    }
  } else {
#pragma unroll
    for (int mi = 0; mi < 4; ++mi)
#pragma unroll
      for (int ni = 0; ni < 4; ++ni)
#pragma unroll
        for (int r = 0; r < 4; ++r) {
          size_t rr = (size_t)(row0 + wm + mi * 16 + 4 * g + r);  // C/D row=4g+reg
          size_t cc = (size_t)(col0 + wn + ni * 16 + q);          // C/D col=lane&15
          if (C_F32) ((float*)Cp)[rr * N + cc] = acc[mi][ni][r];
          else ((ushort_t*)Cp)[rr * N + cc] = f2bf(acc[mi][ni][r]);
        }
  }
}

// Flash attention: block = 128 queries of one (b,h), 8 waves; K/V chunks of
// 128 keys = TWO 64-key sub-chunks computed between ONE barrier pair
// (halves barrier count vs 64-key chunks; 4 staging loads batched per chunk).
// LDS 2x(16+16)KB = 64KB -> still 2 blocks/CU at (512,4); 4MB/XCD L2 fit.
// Swapped QK^T, zero-shuffle P (permuted Vt), defer-max, setprio,
// per-wave sub-chunk skip + interior fast path.
// Blocks 0..15 instead cast w_out f32->bf16 into wob (folds away one launch).
__global__ __launch_bounds__(512, 4) void attn_kernel(const ushort_t* __restrict__ proj,
                                                      const ushort_t* __restrict__ Vt,
                                                      ushort_t* __restrict__ attn_out,
                                                      const float* __restrict__ w_out,
                                                      ushort_t* __restrict__ wob,
                                                      int ostride) {
  const int bid = blockIdx.x;
  if (bid < 16) {                       // embedded w_out cast: 16 blocks
    const int t = bid * 512 + threadIdx.x;
#pragma unroll 4
    for (int k = 0; k < 32; ++k) {
      int i = (k * 8192 + t) * 4;
      float4 v = *(const float4*)(w_out + i);
      ushort4 o;
      o.x = f2bf(v.x); o.y = f2bf(v.y); o.z = f2bf(v.z); o.w = f2bf(v.w);
      *(ushort4*)(wob + i) = o;
    }
    return;
  }
  const int bid2 = bid - 16;

  __shared__ ushort_t Ks[2][2][4096];   // [buf][sub][64 keys x 64 dims]
  __shared__ ushort_t Vs[2][2][4096];   // [buf][sub][64 dims x 64 keys]
  const int tid = threadIdx.x;
  const int wave = tid >> 6;
  const int lane = tid & 63;
  const int g = lane >> 4;
  const int q = lane & 15;
  const int xcd = bid2 & 7;             // XCD-locality swizzle: 8 bh per XCD
  const int j = bid2 >> 3;              // 16 q-tiles per bh
  const int bh = xcd * 8 + (j >> 4);
  const int tile = j & 15;
  const int b = bh >> 4;
  const int h = bh & 15;
  const int q0b = tile * 128;           // block's 128 queries
  const int qw0 = q0b + wave * 16;      // this wave's 16 queries
  const int qglob = qw0 + q;

  const float slope2 = EXP2F(-(float)(h + 1) * 0.5f) * LOG2E;
  const float sc2 = 0.125f * LOG2E;

  const ushort_t* qptr = proj + (size_t)(b * 2048 + qglob) * 3072 + h * 64 + g * 8;
  const bf16x8 qa0 = *(const bf16x8*)(qptr);
  const bf16x8 qa1 = *(const bf16x8*)(qptr + 32);

  // staging: thread -> row tid>>3 (0..63), col-granule (tid&7)^(row&7)
  const int r0 = tid >> 3;
  const int c0s = (((tid & 7) ^ (r0 & 7)) << 3);
  const ushort_t* kgb = proj + (size_t)(b * 2048) * 3072 + 1024 + h * 64;
  const ushort_t* vgb = Vt + (size_t)(bh * 64) * 2048;

  // fragment-read swizzle: rows accessed are 16i+q -> row&7 == q&7
  const int qm = q & 7;
  const int sw0 = ((g ^ qm) << 3);
  const int sw1 = (((g + 4) ^ qm) << 3);

  const f32x4 fzero = {0.f, 0.f, 0.f, 0.f};
  f32x4 acc[4];
#pragma unroll
  for (int t2 = 0; t2 < 4; ++t2) acc[t2] = fzero;
  float m2 = -1e30f;
  float lsum = 0.f;
  const int relbase = qglob - 4 * g;

  int kc_lo = q0b - 512;
  if (kc_lo < 0) kc_lo = 0;             // q0b mult of 128 -> 128-aligned
  const int nch = ((q0b + 127 - kc_lo) >> 7) + 1;   // 128-key chunks

#define STAGE128(bi, kcv)                                                          \
  gload16(kgb + (size_t)((kcv) + r0) * 3072 + c0s, &Ks[bi][0][(size_t)tid * 8]);  \
  gload16(kgb + (size_t)((kcv) + 64 + r0) * 3072 + c0s, &Ks[bi][1][(size_t)tid * 8]); \
  gload16(vgb + (size_t)r0 * 2048 + (kcv) + c0s, &Vs[bi][0][(size_t)tid * 8]);    \
  gload16(vgb + (size_t)r0 * 2048 + (kcv) + 64 + c0s, &Vs[bi][1][(size_t)tid * 8]);

  STAGE128(0, kc_lo)
  __syncthreads();

  for (int c = 0; c < nch; ++c) {
    const int kc = kc_lo + (c << 7);
    if (c + 1 < nch) { STAGE128((c + 1) & 1, kc + 128) }

#pragma unroll
    for (int s = 0; s < 2; ++s) {       // two 64-key sub-chunks, no barrier
      const int kcs = kc + (s << 6);
      const ushort_t* Kb = Ks[c & 1][s];
      const ushort_t* Vb = Vs[c & 1][s];

      // per-wave sub-chunk relevance: any (query,key) with rel in [0,512)
      if (kcs <= qw0 + 15 && kcs >= qw0 - 574) {
        const int rbi = relbase - kcs;
        float p[16];
        float mc = -1e30f;

        if (kcs >= qw0 - 496 && kcs <= qw0 - 63) {
          // interior: every rel valid -> mask-free scores
          const float bb = (float)rbi * slope2;
          __builtin_amdgcn_s_setprio(1);
#pragma unroll
          for (int i = 0; i < 4; ++i) {
            const int row = (i << 4) + q;
            bf16x8 ka = *(const bf16x8*)(Kb + row * 64 + sw0);
            bf16x8 kb = *(const bf16x8*)(Kb + row * 64 + sw1);
            f32x4 si = mfma16(kb, qa1, mfma16(ka, qa0, fzero));
#pragma unroll
            for (int r = 0; r < 4; ++r) {
              float sc = fmaf(si[r], sc2, bb) - (float)((i << 4) + r) * slope2;
              p[(i << 2) + r] = sc;
              mc = fmaxf(mc, sc);
            }
          }
          __builtin_amdgcn_s_setprio(0);
        } else {
          // edge: masked scores (sentinel -1e30 -> exp2 underflows to 0)
          __builtin_amdgcn_s_setprio(1);
#pragma unroll
          for (int i = 0; i < 4; ++i) {
            const int row = (i << 4) + q;
            bf16x8 ka = *(const bf16x8*)(Kb + row * 64 + sw0);
            bf16x8 kb = *(const bf16x8*)(Kb + row * 64 + sw1);
            f32x4 si = mfma16(kb, qa1, mfma16(ka, qa0, fzero));
#pragma unroll
            for (int r = 0; r < 4; ++r) {
              const int rel = rbi - ((i << 4) + r);
              float sc = ((unsigned)rel < 512u) ? fmaf(si[r], sc2, (float)rel * slope2)
                                                : -1e30f;
              p[(i << 2) + r] = sc;
              mc = fmaxf(mc, sc);
            }
          }
          __builtin_amdgcn_s_setprio(0);
        }

        if (__any(mc > m2 + 8.f)) {    // defer-max: rescale only on real bump
          float mg = fmaxf(mc, m2);
          mg = fmaxf(mg, __shfl_xor(mg, 16, 64));
          mg = fmaxf(mg, __shfl_xor(mg, 32, 64));
          const float factor = EXP2F(m2 - mg);
          lsum *= factor;
#pragma unroll
          for (int t2 = 0; t2 < 4; ++t2) acc[t2] *= factor;
          m2 = mg;
        }
#pragma unroll
        for (int i = 0; i < 16; ++i) p[i] = EXP2F(p[i] - m2);  // sentinel -> 0
        float ps0 = (p[0] + p[1]) + (p[2] + p[3]);
        float ps1 = (p[4] + p[5]) + (p[6] + p[7]);
        float ps2 = (p[8] + p[9]) + (p[10] + p[11]);
        float ps3 = (p[12] + p[13]) + (p[14] + p[15]);
        lsum += (ps0 + ps1) + (ps2 + ps3);

        bf16x8 pv0, pv1;                // native casts -> v_cvt_pk_bf16_f32
#pragma unroll
        for (int r = 0; r < 4; ++r) {
          pv0[r] = (__bf16)p[r];       pv0[4 + r] = (__bf16)p[4 + r];
          pv1[r] = (__bf16)p[8 + r];   pv1[4 + r] = (__bf16)p[12 + r];
        }

        __builtin_amdgcn_s_setprio(1);
#pragma unroll
        for (int t2 = 0; t2 < 4; ++t2) {
          const int d = (t2 << 4) + q;
          bf16x8 vf0 = *(const bf16x8*)(Vb + d * 64 + sw0);
          bf16x8 vf1 = *(const bf16x8*)(Vb + d * 64 + sw1);
          acc[t2] = mfma16(vf0, pv0, acc[t2]);
          acc[t2] = mfma16(vf1, pv1, acc[t2]);
        }
        __builtin_amdgcn_s_setprio(0);
      }
    }

    __syncthreads();                   // next chunk ready; cur free to overwrite
  }
#undef STAGE128

  lsum += __shfl_xor(lsum, 16, 64);
  lsum += __shfl_xor(lsum, 32, 64);
  const float inv = 1.f / lsum;

  ushort_t* ob = attn_out + (size_t)(b * 2048 + qglob) * ostride + h * 64;
#pragma unroll
  for (int t2 = 0; t2 < 4; ++t2)
#pragma unroll
    for (int r = 0; r < 4; ++r)
      ob[16 * t2 + 4 * g + r] = f2bf(acc[t2][r] * inv);
}

extern "C" void kernel_launch(void* const* d_in, const int* in_sizes, int n_in,
                              void* d_out, int out_size, void* d_ws, size_t ws_size,
                              hipStream_t stream) {
  const float* x = nullptr;      // 8388608
  const float* w_in = nullptr;   // 3145728
  const float* w_out = nullptr;  // 1048576
  for (int i = 0; i < n_in; ++i) {
    if (in_sizes[i] == 8388608) x = (const float*)d_in[i];
    else if (in_sizes[i] == 3145728) w_in = (const float*)d_in[i];
    else if (in_sizes[i] == 1048576) w_out = (const float*)d_in[i];
  }
  if (!(x && w_in && w_out)) { x = (const float*)d_in[0]; w_in = (const float*)d_in[1]; w_out = (const float*)d_in[2]; }

  char* ws = (char*)d_ws;
  // ws (64 MiB): proj bf16 [8192,3072] @0 (48Mi) — V cols written by attn only.
  //   xb bf16 @48Mi (16.8MB) — dead after gemm1 -> wob aliases it (cast
  //   embedded in the attn launch).
  // d_out scratch (32 MiB): wib bf16 @0 (6.3MB, dead after gemm1);
  //   Vt bf16 @8MiB (16.8MB, gemm1-written, attn-read, dead before gemm2).
  ushort_t* proj = (ushort_t*)(ws);
  ushort_t* xb   = (ushort_t*)(ws + (size_t)50331648);
  ushort_t* wob  = xb;
  ushort_t* wib  = (ushort_t*)d_out;
  ushort_t* Vt   = (ushort_t*)((char*)d_out + (size_t)8388608);

  cast_two<<<11264, 256, 0, stream>>>(x, xb, 8388608, w_in, wib, 3145728);
  gemm_bt<false, true><<<dim3(24, 64), 256, 0, stream>>>(xb, wib, proj, Vt, 3072, 1024, 1024);
  attn_kernel<<<1040, 512, 0, stream>>>(proj, Vt, proj + 2048, w_out, wob, 3072);
  gemm_bt<true, false><<<dim3(8, 64), 256, 0, stream>>>(proj + 2048, wob, d_out, nullptr, 1024, 1024, 3072);
}